// Round 9
// baseline (353.061 us; speedup 1.0000x reference)
//
#include <hip/hip_runtime.h>
#include <hip/hip_bf16.h>

typedef __attribute__((ext_vector_type(8))) short short8;
typedef __attribute__((ext_vector_type(4))) float f32x4;
typedef unsigned short ushort_t;

#define MFMA16(a,b,c) __builtin_amdgcn_mfma_f32_16x16x32_bf16((a),(b),(c),0,0,0)

__device__ __forceinline__ ushort_t f2bf(float x){
  unsigned int u = __builtin_bit_cast(unsigned int, x);
  unsigned int r = (u + 0x7FFFu + ((u >> 16) & 1u)) >> 16;   // RNE
  return (ushort_t)r;
}
__device__ __forceinline__ float bf2f(ushort_t h){
  unsigned int u = ((unsigned int)h) << 16;
  return __builtin_bit_cast(float, u);
}

__device__ __forceinline__ void mat3mul(float* C, const float* A, const float* B){
  #pragma unroll
  for (int i = 0; i < 3; i++)
    #pragma unroll
    for (int k = 0; k < 3; k++)
      C[i*3+k] = A[i*3+0]*B[0*3+k] + A[i*3+1]*B[1*3+k] + A[i*3+2]*B[2*3+k];
}
__device__ __forceinline__ void rotp(float* o, const float* A, float x, float y, float z, const float* t){
  o[0] = A[0]*x + A[1]*y + A[2]*z + t[0];
  o[1] = A[3]*x + A[4]*y + A[5]*z + t[1];
  o[2] = A[6]*x + A[7]*y + A[8]*z + t[2];
}

__global__ __launch_bounds__(64) void poison_kernel(float* out, float val){
  if (threadIdx.x == 0 && blockIdx.x == 0) out[0] = val;
}

// ---------------------------------------------------------------------------
// Pre-swizzle weights into MFMA B-fragment order, SPLIT bf16 (hi + lo planes).
// ---------------------------------------------------------------------------
__global__ __launch_bounds__(256) void preconv_kernel(
    const float* __restrict__ W1, const float* __restrict__ W2, const float* __restrict__ W3,
    ushort_t* __restrict__ W1h, ushort_t* __restrict__ W1l,
    ushort_t* __restrict__ W2h, ushort_t* __restrict__ W2l,
    ushort_t* __restrict__ W3h, ushort_t* __restrict__ W3l)
{
  const int idx = blockIdx.x * 256 + threadIdx.x;   // 0..131071
  { // W1: K=256 (kk 0..7), N=512 (nt 0..31)
    int j = idx & 7, l = (idx >> 3) & 63, kk = (idx >> 9) & 7, nt = idx >> 12;
    int k = kk*32 + (l >> 4)*8 + j, n = nt*16 + (l & 15);
    float w = W1[k*512 + n];
    ushort_t hi = f2bf(w);
    W1h[idx] = hi; W1l[idx] = f2bf(w - bf2f(hi));
  }
  { // W2: K=512 (kk 0..15), N=256 (nt 0..15)
    int j = idx & 7, l = (idx >> 3) & 63, kk = (idx >> 9) & 15, nt = idx >> 13;
    int k = kk*32 + (l >> 4)*8 + j, n = nt*16 + (l & 15);
    float w = W2[k*256 + n];
    ushort_t hi = f2bf(w);
    W2h[idx] = hi; W2l[idx] = f2bf(w - bf2f(hi));
  }
  if (idx < 16384){ // W3: K=256 (kk 0..7), N=31 padded (nt 0..1)
    int j = idx & 7, l = (idx >> 3) & 63, kk = (idx >> 9) & 7, nt = idx >> 12;
    int k = kk*32 + (l >> 4)*8 + j, n = nt*16 + (l & 15);
    float w = (nt < 2 && n < 31) ? W3[k*31 + n] : 0.f;
    ushort_t hi = f2bf(w);
    W3h[idx] = hi; W3l[idx] = f2bf(w - bf2f(hi));
  }
}

// ---------------------------------------------------------------------------
// Fused decoder, 16 rows/block, 256 threads (4 waves), split-bf16 MFMA.
// LDS: regA 2*16*264*2 = 16896 + regB 2*16*72*2 = 4608 + plbuf 2112
//   = 23616 B -> 4 blocks/CU (VGPR-capped at 16 waves/CU).
// ---------------------------------------------------------------------------
__global__ __launch_bounds__(256, 4) void fused_kernel(
    const float* __restrict__ zL, const float* __restrict__ zR,
    const ushort_t* __restrict__ W1h, const ushort_t* __restrict__ W1l,
    const ushort_t* __restrict__ W2h, const ushort_t* __restrict__ W2l,
    const ushort_t* __restrict__ W3h, const ushort_t* __restrict__ W3l,
    const float* __restrict__ b1, const float* __restrict__ b2, const float* __restrict__ b3,
    const float* __restrict__ Jt, const float* __restrict__ sd,
    const float* __restrict__ hc, const float* __restrict__ hm,
    float* __restrict__ out)
{
  __shared__ ushort_t regA[2*16*264];   // z / h2 planes: hi @0, lo @+4224
  __shared__ ushort_t regB[2*16*72];    // h1 planes: hi @0, lo @+1152
  __shared__ float    plbuf[16*33];
  ushort_t* regAhi = regA;
  ushort_t* regAlo = regA + 16*264;
  ushort_t* regBhi = regB;
  ushort_t* regBlo = regB + 16*72;

  const int tid  = threadIdx.x;
  const int lane = tid & 63;
  const int w    = tid >> 6;
  const int lo   = lane & 15;
  const int g    = lane >> 4;
  const int m0   = blockIdx.x * 16;
  const bool right = (m0 >= 65536);
  const float* zsrc = right ? (zR + (size_t)(m0 - 65536) * 256)
                            : (zL + (size_t)m0 * 256);

  // ---- stage z tile (16x256) -> split bf16 planes
  #pragma unroll
  for (int i = 0; i < 4; i++){
    int e = i*1024 + tid*4;
    float4 v = *(const float4*)(zsrc + e);
    int r = e >> 8, c = e & 255;
    ushort_t* dh = &regAhi[r*264 + c];
    ushort_t* dl = &regAlo[r*264 + c];
    float vv[4] = {v.x, v.y, v.z, v.w};
    #pragma unroll
    for (int q = 0; q < 4; q++){
      ushort_t hi = f2bf(vv[q]);
      dh[q] = hi; dl[q] = f2bf(vv[q] - bf2f(hi));
    }
  }
  __syncthreads();

  f32x4 accL2[4];
  #pragma unroll
  for (int b = 0; b < 4; b++)
    accL2[b] = (f32x4){0.f,0.f,0.f,0.f};

  for (int c = 0; c < 8; c++){
    // ---- layer1 (wave owns col-tile nt = c*4+w), 3 independent chains
    {
      const int nt = c*4 + w;
      short8 bh[8], bl[8];
      #pragma unroll
      for (int kk = 0; kk < 8; kk++){
        bh[kk] = *(const short8*)(W1h + (size_t)(nt*8 + kk)*512 + lane*8);
        bl[kk] = *(const short8*)(W1l + (size_t)(nt*8 + kk)*512 + lane*8);
      }
      const float bias = b1[nt*16 + lo];
      f32x4 ahh = (f32x4){0.f,0.f,0.f,0.f};
      f32x4 ahl = (f32x4){0.f,0.f,0.f,0.f};
      f32x4 alh = (f32x4){0.f,0.f,0.f,0.f};
      #pragma unroll
      for (int kk = 0; kk < 8; kk++){
        short8 ah = *(const short8*)&regAhi[lo*264 + kk*32 + g*8];
        short8 al = *(const short8*)&regAlo[lo*264 + kk*32 + g*8];
        ahh = MFMA16(ah, bh[kk], ahh);
        ahl = MFMA16(ah, bl[kk], ahl);
        alh = MFMA16(al, bh[kk], alh);
      }
      #pragma unroll
      for (int i = 0; i < 4; i++){
        float v = fmaxf(ahh[i] + ahl[i] + alh[i] + bias, 0.f);
        ushort_t hi = f2bf(v);
        const int ro = (g*4 + i)*72 + w*16 + lo;
        regBhi[ro] = hi; regBlo[ro] = f2bf(v - bf2f(hi));
      }
    }
    __syncthreads();
    // ---- layer2 partial-K (wave owns cols w*64..+63)
    {
      #pragma unroll
      for (int x = 0; x < 2; x++){
        short8 b2h[4], b2l[4];
        #pragma unroll
        for (int q = 0; q < 4; q++){
          b2h[q] = *(const short8*)(W2h + (size_t)((w*4+q)*16 + c*2 + x)*512 + lane*8);
          b2l[q] = *(const short8*)(W2l + (size_t)((w*4+q)*16 + c*2 + x)*512 + lane*8);
        }
        short8 ah = *(const short8*)&regBhi[lo*72 + x*32 + g*8];
        short8 al = *(const short8*)&regBlo[lo*72 + x*32 + g*8];
        #pragma unroll
        for (int q = 0; q < 4; q++){
          accL2[q] = MFMA16(ah, b2h[q], accL2[q]);
          accL2[q] = MFMA16(ah, b2l[q], accL2[q]);
          accL2[q] = MFMA16(al, b2h[q], accL2[q]);
        }
      }
    }
    __syncthreads();
  }

  // ---- h2 = relu(accL2 + b2) -> split planes in regA (z dead)
  #pragma unroll
  for (int q = 0; q < 4; q++){
    const int col = w*64 + q*16 + lo;
    const float bias = b2[col];
    #pragma unroll
    for (int i = 0; i < 4; i++){
      float v = fmaxf(accL2[q][i] + bias, 0.f);
      ushort_t hi = f2bf(v);
      const int ro = (g*4 + i)*264 + col;
      regAhi[ro] = hi; regAlo[ro] = f2bf(v - bf2f(hi));
    }
  }
  __syncthreads();

  // ---- layer3: waves 0,1 -> n-tile nn = w; 3 chains
  if (w < 2){
    const int nn = w;
    f32x4 ahh = (f32x4){0.f,0.f,0.f,0.f};
    f32x4 ahl = (f32x4){0.f,0.f,0.f,0.f};
    f32x4 alh = (f32x4){0.f,0.f,0.f,0.f};
    #pragma unroll
    for (int kk = 0; kk < 8; kk++){
      short8 ah = *(const short8*)&regAhi[lo*264 + kk*32 + g*8];
      short8 al = *(const short8*)&regAlo[lo*264 + kk*32 + g*8];
      short8 bh = *(const short8*)(W3h + (size_t)(nn*8 + kk)*512 + lane*8);
      short8 bl = *(const short8*)(W3l + (size_t)(nn*8 + kk)*512 + lane*8);
      ahh = MFMA16(ah, bh, ahh);
      ahl = MFMA16(ah, bl, ahl);
      alh = MFMA16(al, bh, alh);
    }
    const int col = nn*16 + lo;
    const float bias = (col < 31) ? b3[col] : 0.f;
    #pragma unroll
    for (int i = 0; i < 4; i++)
      plbuf[(g*4 + i)*33 + col] = ahh[i] + ahl[i] + alh[i] + bias;
  }
  __syncthreads();
  const float* pl = plbuf;

  // ---- FK with inline rodrigues: one thread per row
  if (tid < 16){
    const int r = tid;
    float p15[15];
    #pragma unroll
    for (int d = 0; d < 15; d++) p15[d] = pl[r*33 + d];
    float sh[10];
    #pragma unroll
    for (int d = 0; d < 10; d++) sh[d] = pl[r*33 + 15 + d];
    const float trx = pl[r*33+28], tr_y = pl[r*33+29], trz = pl[r*33+30];

    float J[16][3];
    #pragma unroll
    for (int jj = 0; jj < 16; jj++){
      #pragma unroll
      for (int k2 = 0; k2 < 3; k2++){
        float v = Jt[jj*3 + k2];
        #pragma unroll
        for (int d = 0; d < 10; d++) v = fmaf(sd[(jj*3 + k2)*10 + d], sh[d], v);
        J[jj][k2] = v;
      }
    }
    if (!right){
      #pragma unroll
      for (int jj = 0; jj < 16; jj++) J[jj][0] = -J[jj][0];
    }

    auto rod = [](float ax, float ay, float az, float* R){
      float th = sqrtf(ax*ax + ay*ay + az*az + 1e-12f);
      float inv = 1.0f / th;
      float kx = ax*inv, ky = ay*inv, kz = az*inv;
      float st = __sinf(th), ct = __cosf(th);
      float omc = 1.0f - ct;
      R[0] = ct + omc*kx*kx;      R[1] = omc*kx*ky - st*kz;  R[2] = omc*kx*kz + st*ky;
      R[3] = omc*kx*ky + st*kz;   R[4] = ct + omc*ky*ky;     R[5] = omc*ky*kz - st*kx;
      R[6] = omc*kx*kz - st*ky;   R[7] = omc*ky*kz + st*kx;  R[8] = ct + omc*kz*kz;
    };
    auto axis_rod = [&](int j, float* R){
      const int base = 3*(j-1);
      float s0 = hm[base+0], s1 = hm[base+1], s2 = hm[base+2];
      #pragma unroll
      for (int d = 0; d < 15; d++){
        float pv = p15[d];
        s0 = fmaf(pv, hc[d*45 + base+0], s0);
        s1 = fmaf(pv, hc[d*45 + base+1], s1);
        s2 = fmaf(pv, hc[d*45 + base+2], s2);
      }
      rod(s0, s1, s2, R);
    };

    float R0[9];
    rod(pl[r*33+25], pl[r*33+26], pl[r*33+27], R0);

    const size_t ob = (right ? (size_t)3145728 : (size_t)0)
                    + (size_t)(m0 - (right ? 65536 : 0) + r) * 48;
    float t0[3] = {J[0][0], J[0][1], J[0][2]};
    out[ob+0] = t0[0]+trx; out[ob+1] = t0[1]+tr_y; out[ob+2] = t0[2]+trz;
    #pragma unroll
    for (int f = 0; f < 5; f++){
      const int i1 = 3*f+1, i2 = 3*f+2, i3 = 3*f+3;
      float R1[9], R2[9], Rw1[9], Rw2[9], t1[3], t2[3], t3[3];
      axis_rod(i1, R1);
      axis_rod(i2, R2);
      mat3mul(Rw1, R0, R1);
      rotp(t1, R0,  J[i1][0]-J[0][0],  J[i1][1]-J[0][1],  J[i1][2]-J[0][2],  t0);
      mat3mul(Rw2, Rw1, R2);
      rotp(t2, Rw1, J[i2][0]-J[i1][0], J[i2][1]-J[i1][1], J[i2][2]-J[i1][2], t1);
      rotp(t3, Rw2, J[i3][0]-J[i2][0], J[i3][1]-J[i2][1], J[i3][2]-J[i2][2], t2);
      out[ob + i1*3+0] = t1[0]+trx; out[ob + i1*3+1] = t1[1]+tr_y; out[ob + i1*3+2] = t1[2]+trz;
      out[ob + i2*3+0] = t2[0]+trx; out[ob + i2*3+1] = t2[1]+tr_y; out[ob + i2*3+2] = t2[2]+trz;
      out[ob + i3*3+0] = t3[0]+trx; out[ob + i3*3+1] = t3[1]+tr_y; out[ob + i3*3+2] = t3[2]+trz;
    }
  }
}

extern "C" void kernel_launch(void* const* d_in, const int* in_sizes, int n_in,
                              void* d_out, int out_size, void* d_ws, size_t ws_size,
                              hipStream_t stream) {
  const float* zL = (const float*)d_in[0];
  const float* zR = (const float*)d_in[1];
  const float* W1 = (const float*)d_in[2];
  const float* b1 = (const float*)d_in[3];
  const float* W2 = (const float*)d_in[4];
  const float* b2 = (const float*)d_in[5];
  const float* W3 = (const float*)d_in[6];
  const float* b3 = (const float*)d_in[7];
  const float* Jt = (const float*)d_in[8];
  const float* sd = (const float*)d_in[9];
  const float* hc = (const float*)d_in[10];
  const float* hm = (const float*)d_in[11];

  float* out = (float*)d_out;

  if (ws_size < 1114112){
    poison_kernel<<<1, 64, 0, stream>>>(out, 20480.f);
    return;
  }

  ushort_t* W1h = (ushort_t*)d_ws;
  ushort_t* W1l = W1h + 131072;
  ushort_t* W2h = W1l + 131072;
  ushort_t* W2l = W2h + 131072;
  ushort_t* W3h = W2l + 131072;
  ushort_t* W3l = W3h + 16384;

  preconv_kernel<<<512, 256, 0, stream>>>(W1, W2, W3, W1h, W1l, W2h, W2l, W3h, W3l);
  fused_kernel<<<8192, 256, 0, stream>>>(zL, zR, W1h, W1l, W2h, W2l, W3h, W3l,
                                         b1, b2, b3, Jt, sd, hc, hm, out);
}

// Round 10
// 269.150 us; speedup vs baseline: 1.3118x; 1.3118x over previous
//
#include <hip/hip_runtime.h>
#include <hip/hip_bf16.h>

typedef __attribute__((ext_vector_type(8))) short short8;
typedef __attribute__((ext_vector_type(4))) float f32x4;
typedef unsigned short ushort_t;

#define MFMA16(a,b,c) __builtin_amdgcn_mfma_f32_16x16x32_bf16((a),(b),(c),0,0,0)

__device__ __forceinline__ ushort_t f2bf(float x){
  unsigned int u = __builtin_bit_cast(unsigned int, x);
  unsigned int r = (u + 0x7FFFu + ((u >> 16) & 1u)) >> 16;   // RNE
  return (ushort_t)r;
}
__device__ __forceinline__ float bf2f(ushort_t h){
  unsigned int u = ((unsigned int)h) << 16;
  return __builtin_bit_cast(float, u);
}

__device__ __forceinline__ void mat3mul(float* C, const float* A, const float* B){
  #pragma unroll
  for (int i = 0; i < 3; i++)
    #pragma unroll
    for (int k = 0; k < 3; k++)
      C[i*3+k] = A[i*3+0]*B[0*3+k] + A[i*3+1]*B[1*3+k] + A[i*3+2]*B[2*3+k];
}
__device__ __forceinline__ void rotp(float* o, const float* A, float x, float y, float z, const float* t){
  o[0] = A[0]*x + A[1]*y + A[2]*z + t[0];
  o[1] = A[3]*x + A[4]*y + A[5]*z + t[1];
  o[2] = A[6]*x + A[7]*y + A[8]*z + t[2];
}

__global__ __launch_bounds__(64) void poison_kernel(float* out, float val){
  if (threadIdx.x == 0 && blockIdx.x == 0) out[0] = val;
}

// ---------------------------------------------------------------------------
// Pre-swizzle weights into MFMA B-fragment order, SPLIT bf16 (hi + lo planes).
// ---------------------------------------------------------------------------
__global__ __launch_bounds__(256) void preconv_kernel(
    const float* __restrict__ W1, const float* __restrict__ W2, const float* __restrict__ W3,
    ushort_t* __restrict__ W1h, ushort_t* __restrict__ W1l,
    ushort_t* __restrict__ W2h, ushort_t* __restrict__ W2l,
    ushort_t* __restrict__ W3h, ushort_t* __restrict__ W3l)
{
  const int idx = blockIdx.x * 256 + threadIdx.x;   // 0..131071
  { // W1: K=256 (kk 0..7), N=512 (nt 0..31)
    int j = idx & 7, l = (idx >> 3) & 63, kk = (idx >> 9) & 7, nt = idx >> 12;
    int k = kk*32 + (l >> 4)*8 + j, n = nt*16 + (l & 15);
    float w = W1[k*512 + n];
    ushort_t hi = f2bf(w);
    W1h[idx] = hi; W1l[idx] = f2bf(w - bf2f(hi));
  }
  { // W2: K=512 (kk 0..15), N=256 (nt 0..15)
    int j = idx & 7, l = (idx >> 3) & 63, kk = (idx >> 9) & 15, nt = idx >> 13;
    int k = kk*32 + (l >> 4)*8 + j, n = nt*16 + (l & 15);
    float w = W2[k*256 + n];
    ushort_t hi = f2bf(w);
    W2h[idx] = hi; W2l[idx] = f2bf(w - bf2f(hi));
  }
  if (idx < 16384){ // W3: K=256 (kk 0..7), N=31 padded (nt 0..1)
    int j = idx & 7, l = (idx >> 3) & 63, kk = (idx >> 9) & 7, nt = idx >> 12;
    int k = kk*32 + (l >> 4)*8 + j, n = nt*16 + (l & 15);
    float w = (nt < 2 && n < 31) ? W3[k*31 + n] : 0.f;
    ushort_t hi = f2bf(w);
    W3h[idx] = hi; W3l[idx] = f2bf(w - bf2f(hi));
  }
}

// ---------------------------------------------------------------------------
// Fused decoder, 32 rows/block, 256 threads (4 waves), split-bf16 MFMA,
// software-pipelined weight loads:
//   - W1[c] preloaded before the chunk (refilled in-place during layer2(c-1))
//   - W2[c] loads issued inside layer1(c)'s MFMA phase (two halves)
//   - W3 loads issued during the h2-writeback phase
// LDS: regA 33792 + regB 9216 + plbuf 4224 = 47232 B.
// ---------------------------------------------------------------------------
__global__ __launch_bounds__(256, 2) void fused_kernel(
    const float* __restrict__ zL, const float* __restrict__ zR,
    const ushort_t* __restrict__ W1h, const ushort_t* __restrict__ W1l,
    const ushort_t* __restrict__ W2h, const ushort_t* __restrict__ W2l,
    const ushort_t* __restrict__ W3h, const ushort_t* __restrict__ W3l,
    const float* __restrict__ b1, const float* __restrict__ b2, const float* __restrict__ b3,
    const float* __restrict__ Jt, const float* __restrict__ sd,
    const float* __restrict__ hc, const float* __restrict__ hm,
    float* __restrict__ out)
{
  __shared__ ushort_t regA[2*32*264];   // z / h2 planes: hi @0, lo @+8448
  __shared__ ushort_t regB[2*32*72];    // h1 planes: hi @0, lo @+2304
  __shared__ float    plbuf[32*33];
  ushort_t* regAhi = regA;
  ushort_t* regAlo = regA + 32*264;
  ushort_t* regBhi = regB;
  ushort_t* regBlo = regB + 32*72;

  const int tid  = threadIdx.x;
  const int lane = tid & 63;
  const int w    = tid >> 6;
  const int lo   = lane & 15;
  const int g    = lane >> 4;
  const int m0   = blockIdx.x * 32;
  const bool right = (m0 >= 65536);
  const float* zsrc = right ? (zR + (size_t)(m0 - 65536) * 256)
                            : (zL + (size_t)m0 * 256);

  // ---- prologue: issue W1[c=0] loads (latency covered by z staging + barrier)
  short8 bh[8], bl[8];
  #pragma unroll
  for (int kk = 0; kk < 8; kk++){
    bh[kk] = *(const short8*)(W1h + (size_t)((0*4 + w)*8 + kk)*512 + lane*8);
    bl[kk] = *(const short8*)(W1l + (size_t)((0*4 + w)*8 + kk)*512 + lane*8);
  }

  // ---- stage z tile (32x256) -> split bf16 planes
  #pragma unroll
  for (int i = 0; i < 8; i++){
    int e = i*1024 + tid*4;
    float4 v = *(const float4*)(zsrc + e);
    int r = e >> 8, c = e & 255;
    ushort_t* dh = &regAhi[r*264 + c];
    ushort_t* dl = &regAlo[r*264 + c];
    float vv[4] = {v.x, v.y, v.z, v.w};
    #pragma unroll
    for (int q = 0; q < 4; q++){
      ushort_t hi = f2bf(vv[q]);
      dh[q] = hi; dl[q] = f2bf(vv[q] - bf2f(hi));
    }
  }
  __syncthreads();

  f32x4 accL2[2][4];
  #pragma unroll
  for (int a = 0; a < 2; a++)
    #pragma unroll
    for (int b = 0; b < 4; b++)
      accL2[a][b] = (f32x4){0.f,0.f,0.f,0.f};

  #pragma unroll
  for (int c = 0; c < 8; c++){
    const int nt = c*4 + w;
    const float bias1 = b1[nt*16 + lo];

    // ---- issue W2[c] x=0 half (used in layer2 below)
    short8 b2h0[4], b2l0[4];
    #pragma unroll
    for (int q = 0; q < 4; q++){
      b2h0[q] = *(const short8*)(W2h + (size_t)((w*4+q)*16 + c*2 + 0)*512 + lane*8);
      b2l0[q] = *(const short8*)(W2l + (size_t)((w*4+q)*16 + c*2 + 0)*512 + lane*8);
    }

    // ---- layer1 rt=0 (uses preloaded W1[c])
    {
      f32x4 ahh = (f32x4){0.f,0.f,0.f,0.f};
      f32x4 ahl = (f32x4){0.f,0.f,0.f,0.f};
      f32x4 alh = (f32x4){0.f,0.f,0.f,0.f};
      #pragma unroll
      for (int kk = 0; kk < 8; kk++){
        short8 ah = *(const short8*)&regAhi[(0*16 + lo)*264 + kk*32 + g*8];
        short8 al = *(const short8*)&regAlo[(0*16 + lo)*264 + kk*32 + g*8];
        ahh = MFMA16(ah, bh[kk], ahh);
        ahl = MFMA16(ah, bl[kk], ahl);
        alh = MFMA16(al, bh[kk], alh);
      }
      #pragma unroll
      for (int i = 0; i < 4; i++){
        float v = fmaxf(ahh[i] + ahl[i] + alh[i] + bias1, 0.f);
        ushort_t hi = f2bf(v);
        const int ro = (0*16 + g*4 + i)*72 + w*16 + lo;
        regBhi[ro] = hi; regBlo[ro] = f2bf(v - bf2f(hi));
      }
    }

    // ---- issue W2[c] x=1 half
    short8 b2h1[4], b2l1[4];
    #pragma unroll
    for (int q = 0; q < 4; q++){
      b2h1[q] = *(const short8*)(W2h + (size_t)((w*4+q)*16 + c*2 + 1)*512 + lane*8);
      b2l1[q] = *(const short8*)(W2l + (size_t)((w*4+q)*16 + c*2 + 1)*512 + lane*8);
    }

    // ---- layer1 rt=1
    {
      f32x4 ahh = (f32x4){0.f,0.f,0.f,0.f};
      f32x4 ahl = (f32x4){0.f,0.f,0.f,0.f};
      f32x4 alh = (f32x4){0.f,0.f,0.f,0.f};
      #pragma unroll
      for (int kk = 0; kk < 8; kk++){
        short8 ah = *(const short8*)&regAhi[(1*16 + lo)*264 + kk*32 + g*8];
        short8 al = *(const short8*)&regAlo[(1*16 + lo)*264 + kk*32 + g*8];
        ahh = MFMA16(ah, bh[kk], ahh);
        ahl = MFMA16(ah, bl[kk], ahl);
        alh = MFMA16(al, bh[kk], alh);
      }
      #pragma unroll
      for (int i = 0; i < 4; i++){
        float v = fmaxf(ahh[i] + ahl[i] + alh[i] + bias1, 0.f);
        ushort_t hi = f2bf(v);
        const int ro = (1*16 + g*4 + i)*72 + w*16 + lo;
        regBhi[ro] = hi; regBlo[ro] = f2bf(v - bf2f(hi));
      }
    }
    __syncthreads();

    // ---- layer2 x=0; W1[c] regs are dead -> refill with W1[c+1] kk=0..3
    if (c < 7){
      #pragma unroll
      for (int kk = 0; kk < 4; kk++){
        bh[kk] = *(const short8*)(W1h + (size_t)(((c+1)*4 + w)*8 + kk)*512 + lane*8);
        bl[kk] = *(const short8*)(W1l + (size_t)(((c+1)*4 + w)*8 + kk)*512 + lane*8);
      }
    }
    #pragma unroll
    for (int rt = 0; rt < 2; rt++){
      short8 ah = *(const short8*)&regBhi[(rt*16 + lo)*72 + 0*32 + g*8];
      short8 al = *(const short8*)&regBlo[(rt*16 + lo)*72 + 0*32 + g*8];
      #pragma unroll
      for (int q = 0; q < 4; q++){
        accL2[rt][q] = MFMA16(ah, b2h0[q], accL2[rt][q]);
        accL2[rt][q] = MFMA16(ah, b2l0[q], accL2[rt][q]);
        accL2[rt][q] = MFMA16(al, b2h0[q], accL2[rt][q]);
      }
    }

    // ---- layer2 x=1; refill W1[c+1] kk=4..7
    if (c < 7){
      #pragma unroll
      for (int kk = 4; kk < 8; kk++){
        bh[kk] = *(const short8*)(W1h + (size_t)(((c+1)*4 + w)*8 + kk)*512 + lane*8);
        bl[kk] = *(const short8*)(W1l + (size_t)(((c+1)*4 + w)*8 + kk)*512 + lane*8);
      }
    }
    #pragma unroll
    for (int rt = 0; rt < 2; rt++){
      short8 ah = *(const short8*)&regBhi[(rt*16 + lo)*72 + 1*32 + g*8];
      short8 al = *(const short8*)&regBlo[(rt*16 + lo)*72 + 1*32 + g*8];
      #pragma unroll
      for (int q = 0; q < 4; q++){
        accL2[rt][q] = MFMA16(ah, b2h1[q], accL2[rt][q]);
        accL2[rt][q] = MFMA16(ah, b2l1[q], accL2[rt][q]);
        accL2[rt][q] = MFMA16(al, b2h1[q], accL2[rt][q]);
      }
    }
    __syncthreads();
  }

  // ---- issue W3 loads (latency covered by h2 writeback + barrier)
  const int rw = w & 1, nn = w >> 1;
  short8 w3h[8], w3l[8];
  #pragma unroll
  for (int kk = 0; kk < 8; kk++){
    w3h[kk] = *(const short8*)(W3h + (size_t)(nn*8 + kk)*512 + lane*8);
    w3l[kk] = *(const short8*)(W3l + (size_t)(nn*8 + kk)*512 + lane*8);
  }

  // ---- h2 = relu(accL2 + b2) -> split planes in regA (z dead)
  #pragma unroll
  for (int rt = 0; rt < 2; rt++){
    #pragma unroll
    for (int q = 0; q < 4; q++){
      const int col = w*64 + q*16 + lo;
      const float bias = b2[col];
      #pragma unroll
      for (int i = 0; i < 4; i++){
        float v = fmaxf(accL2[rt][q][i] + bias, 0.f);
        ushort_t hi = f2bf(v);
        const int ro = (rt*16 + g*4 + i)*264 + col;
        regAhi[ro] = hi; regAlo[ro] = f2bf(v - bf2f(hi));
      }
    }
  }
  __syncthreads();

  // ---- layer3: wave w -> row-tile rw, n-tile nn; 3 chains
  {
    f32x4 ahh = (f32x4){0.f,0.f,0.f,0.f};
    f32x4 ahl = (f32x4){0.f,0.f,0.f,0.f};
    f32x4 alh = (f32x4){0.f,0.f,0.f,0.f};
    #pragma unroll
    for (int kk = 0; kk < 8; kk++){
      short8 ah = *(const short8*)&regAhi[(rw*16 + lo)*264 + kk*32 + g*8];
      short8 al = *(const short8*)&regAlo[(rw*16 + lo)*264 + kk*32 + g*8];
      ahh = MFMA16(ah, w3h[kk], ahh);
      ahl = MFMA16(ah, w3l[kk], ahl);
      alh = MFMA16(al, w3h[kk], alh);
    }
    const int col = nn*16 + lo;
    const float bias = (col < 31) ? b3[col] : 0.f;
    #pragma unroll
    for (int i = 0; i < 4; i++)
      plbuf[(rw*16 + g*4 + i)*33 + col] = ahh[i] + ahl[i] + alh[i] + bias;
  }
  __syncthreads();
  const float* pl = plbuf;

  // ---- FK with inline rodrigues: one thread per row
  if (tid < 32){
    const int r = tid;
    float p15[15];
    #pragma unroll
    for (int d = 0; d < 15; d++) p15[d] = pl[r*33 + d];
    float sh[10];
    #pragma unroll
    for (int d = 0; d < 10; d++) sh[d] = pl[r*33 + 15 + d];
    const float trx = pl[r*33+28], tr_y = pl[r*33+29], trz = pl[r*33+30];

    float J[16][3];
    #pragma unroll
    for (int jj = 0; jj < 16; jj++){
      #pragma unroll
      for (int k2 = 0; k2 < 3; k2++){
        float v = Jt[jj*3 + k2];
        #pragma unroll
        for (int d = 0; d < 10; d++) v = fmaf(sd[(jj*3 + k2)*10 + d], sh[d], v);
        J[jj][k2] = v;
      }
    }
    if (!right){
      #pragma unroll
      for (int jj = 0; jj < 16; jj++) J[jj][0] = -J[jj][0];
    }

    auto rod = [](float ax, float ay, float az, float* R){
      float th = sqrtf(ax*ax + ay*ay + az*az + 1e-12f);
      float inv = 1.0f / th;
      float kx = ax*inv, ky = ay*inv, kz = az*inv;
      float st = __sinf(th), ct = __cosf(th);
      float omc = 1.0f - ct;
      R[0] = ct + omc*kx*kx;      R[1] = omc*kx*ky - st*kz;  R[2] = omc*kx*kz + st*ky;
      R[3] = omc*kx*ky + st*kz;   R[4] = ct + omc*ky*ky;     R[5] = omc*ky*kz - st*kx;
      R[6] = omc*kx*kz - st*ky;   R[7] = omc*ky*kz + st*kx;  R[8] = ct + omc*kz*kz;
    };
    auto axis_rod = [&](int j, float* R){
      const int base = 3*(j-1);
      float s0 = hm[base+0], s1 = hm[base+1], s2 = hm[base+2];
      #pragma unroll
      for (int d = 0; d < 15; d++){
        float pv = p15[d];
        s0 = fmaf(pv, hc[d*45 + base+0], s0);
        s1 = fmaf(pv, hc[d*45 + base+1], s1);
        s2 = fmaf(pv, hc[d*45 + base+2], s2);
      }
      rod(s0, s1, s2, R);
    };

    float R0[9];
    rod(pl[r*33+25], pl[r*33+26], pl[r*33+27], R0);

    const size_t ob = (right ? (size_t)3145728 : (size_t)0)
                    + (size_t)(m0 - (right ? 65536 : 0) + r) * 48;
    float t0[3] = {J[0][0], J[0][1], J[0][2]};
    out[ob+0] = t0[0]+trx; out[ob+1] = t0[1]+tr_y; out[ob+2] = t0[2]+trz;
    #pragma unroll
    for (int f = 0; f < 5; f++){
      const int i1 = 3*f+1, i2 = 3*f+2, i3 = 3*f+3;
      float R1[9], R2[9], Rw1[9], Rw2[9], t1[3], t2[3], t3[3];
      axis_rod(i1, R1);
      axis_rod(i2, R2);
      mat3mul(Rw1, R0, R1);
      rotp(t1, R0,  J[i1][0]-J[0][0],  J[i1][1]-J[0][1],  J[i1][2]-J[0][2],  t0);
      mat3mul(Rw2, Rw1, R2);
      rotp(t2, Rw1, J[i2][0]-J[i1][0], J[i2][1]-J[i1][1], J[i2][2]-J[i1][2], t1);
      rotp(t3, Rw2, J[i3][0]-J[i2][0], J[i3][1]-J[i2][1], J[i3][2]-J[i2][2], t2);
      out[ob + i1*3+0] = t1[0]+trx; out[ob + i1*3+1] = t1[1]+tr_y; out[ob + i1*3+2] = t1[2]+trz;
      out[ob + i2*3+0] = t2[0]+trx; out[ob + i2*3+1] = t2[1]+tr_y; out[ob + i2*3+2] = t2[2]+trz;
      out[ob + i3*3+0] = t3[0]+trx; out[ob + i3*3+1] = t3[1]+tr_y; out[ob + i3*3+2] = t3[2]+trz;
    }
  }
}

extern "C" void kernel_launch(void* const* d_in, const int* in_sizes, int n_in,
                              void* d_out, int out_size, void* d_ws, size_t ws_size,
                              hipStream_t stream) {
  const float* zL = (const float*)d_in[0];
  const float* zR = (const float*)d_in[1];
  const float* W1 = (const float*)d_in[2];
  const float* b1 = (const float*)d_in[3];
  const float* W2 = (const float*)d_in[4];
  const float* b2 = (const float*)d_in[5];
  const float* W3 = (const float*)d_in[6];
  const float* b3 = (const float*)d_in[7];
  const float* Jt = (const float*)d_in[8];
  const float* sd = (const float*)d_in[9];
  const float* hc = (const float*)d_in[10];
  const float* hm = (const float*)d_in[11];

  float* out = (float*)d_out;

  if (ws_size < 1114112){
    poison_kernel<<<1, 64, 0, stream>>>(out, 20480.f);
    return;
  }

  ushort_t* W1h = (ushort_t*)d_ws;
  ushort_t* W1l = W1h + 131072;
  ushort_t* W2h = W1l + 131072;
  ushort_t* W2l = W2h + 131072;
  ushort_t* W3h = W2l + 131072;
  ushort_t* W3l = W3h + 16384;

  preconv_kernel<<<512, 256, 0, stream>>>(W1, W2, W3, W1h, W1l, W2h, W2l, W3h, W3l);
  fused_kernel<<<4096, 256, 0, stream>>>(zL, zR, W1h, W1l, W2h, W2l, W3h, W3l,
                                         b1, b2, b3, Jt, sd, hc, hm, out);
}